// Round 16
// baseline (6927.515 us; speedup 1.0000x reference)
//
#include <hip/hip_runtime.h>
#include <hip/hip_cooperative_groups.h>
#include <math.h>

constexpr int T_ = 512, B_ = 128, D_ = 512, V_ = 33, E_ = 128;
constexpr int G4 = 4 * D_;          // 2048
constexpr int BD = B_ * D_;         // 65536
constexpr int BV = B_ * V_;         // 4224
constexpr int TWO_D = 2 * D_;       // 1024
constexpr int WIMG_HALF = 1048576;  // shorts per (hi|lo) plane of W image

typedef __attribute__((ext_vector_type(8))) short short8;
typedef __attribute__((ext_vector_type(4))) float floatx4;

__device__ inline short f2bf(float f) {
    unsigned u = __float_as_uint(f);
    unsigned r = (u + 0x7fff + ((u >> 16) & 1)) >> 16;
    return (short)r;
}
__device__ inline float bf2f(short s) {
    return __uint_as_float(((unsigned)(unsigned short)s) << 16);
}

// ---------------------------------------------------------------- prep
__global__ void prep_kernel(const float* __restrict__ b_emb, const float* __restrict__ W_ih,
                            const float* __restrict__ b_ih, const float* __restrict__ b_hh,
                            const float* __restrict__ W_out,
                            float* __restrict__ g0, float* __restrict__ WoT) {
    int idx = blockIdx.x * 256 + threadIdx.x;
    if (idx < G4) {
        float acc = b_ih[idx] + b_hh[idx];
        for (int e = 0; e < E_; ++e) acc = fmaf(b_emb[e], W_ih[e * G4 + idx], acc);
        g0[idx] = acc;
    } else {
        int k = idx - G4;
        if (k < V_ * TWO_D) {
            int v = k / TWO_D, j = k % TWO_D;
            WoT[v * TWO_D + j] = W_out[j * V_ + v];
        }
    }
}

// ---------------------------------------------------------------- prep2: W fragment image
__global__ void prep2_kernel(const float* __restrict__ Whh, short* __restrict__ Wimg) {
    int idx = blockIdx.x * 256 + threadIdx.x;   // 2048*512 total
    int G = idx & 2047, k = idx >> 11;
    float v = Whh[(size_t)k * G4 + G];
    short hi = f2bf(v);
    short lo = f2bf(v - bf2f(hi));
    int g = G >> 9, cc = G & 511, n = cc >> 4, c = cc & 15;
    int kt = k >> 5, kg = (k >> 3) & 3, j = k & 7;
    int lane = kg * 16 + c;
    size_t dst = ((size_t)((n * 4 + g) * 16 + kt) * 64 + lane) * 8 + j;
    Wimg[dst] = hi;
    Wimg[dst + WIMG_HALF] = lo;
}

// ---------------------------------------------------------------- rowsum (f64)
__global__ void rowsum_kernel(const float* __restrict__ enc, double* __restrict__ rowsum) {
    int wave = threadIdx.x >> 6, lane = threadIdx.x & 63;
    int row = blockIdx.x * 4 + wave;
    const float* p = enc + (size_t)row * D_;
    double s = 0.0;
    #pragma unroll
    for (int k = 0; k < 8; ++k) s += (double)p[k * 64 + lane];
    for (int off = 32; off; off >>= 1) s += __shfl_down(s, off, 64);
    if (lane == 0) rowsum[row] = s;
}

// ---------------------------------------------------------------- lstm (persistent, XCD-local group barriers, adaptive)
// 256 blocks x 256 threads (cooperative, 1/CU). Block: m = blk&7, n = blk>>3.
// Init: blocks publish their HW_REG_XCC_ID per m-group via MALL atomics.
// FAST path (every group on ONE XCD and the 8 groups cover 8 distinct XCDs):
//   h exchange via plain write-through stores (in XCD L2 after vmcnt(0)) +
//   volatile (cache-bypassing) consumer loads — NO fences.
// FALLBACK (any doubt): R9's proven fenced protocol (correct, slow).
// Barrier = R13-proven relaxed-atomic flags, fresh per (t,m).
// Per-step math, MFMA order, epilogue bit-identical to R15; c in register.
__global__ void __launch_bounds__(256, 1) lstm_persist(const short* __restrict__ Wimg,
                                                       const float* __restrict__ g0,
                                                       float* __restrict__ Hs,
                                                       short* __restrict__ hb,
                                                       unsigned* __restrict__ bar,
                                                       unsigned* __restrict__ xinfo) {
    __shared__ short Alds[16384];            // 32 KB: A hi [0,8192) + lo [8192,16384)
    __shared__ float xch[4][64][4];
    __shared__ int fastflag;
    const int tid = threadIdx.x;
    const int l = tid & 63, g = tid >> 6;
    const int m = blockIdx.x & 7, n = blockIdx.x >> 3;
    const int col = l & 15, kg = l >> 4;
    const float g0v = g0[g * 512 + n * 16 + col];
    const short* __restrict__ bbase = Wimg + ((size_t)((n * 4 + g) * 16) * 64 + l) * 8;
    const int epos = (m * 16 + kg * 4 + g) * 512 + n * 16 + col;

    // ---- init: determine whether each m-group is XCD-local (adaptive gate)
    if (tid == 0) {
        unsigned xcc = __builtin_amdgcn_s_getreg(6164) & 0xFu;  // HW_REG_XCC_ID(20), off 0, sz 4
        __hip_atomic_fetch_or(&xinfo[m * 16], 1u << xcc, __ATOMIC_RELAXED, __HIP_MEMORY_SCOPE_AGENT);
        __hip_atomic_fetch_add(&xinfo[128], 1u, __ATOMIC_RELAXED, __HIP_MEMORY_SCOPE_AGENT);
        while (__hip_atomic_load(&xinfo[128], __ATOMIC_RELAXED, __HIP_MEMORY_SCOPE_AGENT) < 256u)
            __builtin_amdgcn_s_sleep(1);
        unsigned orall = 0;
        int ok = 1;
        for (int i = 0; i < 8; ++i) {
            unsigned mk = __hip_atomic_load(&xinfo[i * 16], __ATOMIC_RELAXED, __HIP_MEMORY_SCOPE_AGENT);
            orall |= mk;
            if (__popc(mk) != 1) ok = 0;
        }
        if (orall != 0xFFu) ok = 0;   // require 8 groups on 8 distinct XCDs (spoof-proof)
        fastflag = ok;
    }
    __syncthreads();
    const bool fast = (fastflag != 0);

    float creg = 0.f;

    for (int t = 0; t < T_; ++t) {
        floatx4 acc = {0.f, 0.f, 0.f, 0.f};
        if (t > 0) {
            // wait for the 32 producers of row-group m
            if (l == 0) {
                const unsigned* flag = bar + (size_t)((t - 1) * 8 + m) * 16;
                while (__hip_atomic_load(flag, __ATOMIC_RELAXED, __HIP_MEMORY_SCOPE_AGENT) < 32u)
                    __builtin_amdgcn_s_sleep(2);
                if (!fast) __threadfence();
            }
            __syncthreads();
            // stage A (32KB, swizzled): volatile loads bypass stale caches
            {
                const short* ah = hb + (size_t)((t - 1) & 1) * 131072 + m * 8192;
                const short* al = ah + 65536;
                #pragma unroll
                for (int it = 0; it < 4; ++it) {
                    int u = it * 256 + tid;                              // 16B unit 0..1023
                    int s = (u & ~63) | ((u & 63) ^ ((u >> 6) & 7));     // swizzled LDS unit
                    const unsigned long long* ahq = (const unsigned long long*)(ah + u * 8);
                    const unsigned long long* alq = (const unsigned long long*)(al + u * 8);
                    unsigned long long h0 = *(const volatile unsigned long long*)(ahq + 0);
                    unsigned long long h1 = *(const volatile unsigned long long*)(ahq + 1);
                    unsigned long long l0 = *(const volatile unsigned long long*)(alq + 0);
                    unsigned long long l1 = *(const volatile unsigned long long*)(alq + 1);
                    unsigned long long* dh = (unsigned long long*)&Alds[s * 8];
                    unsigned long long* dl = (unsigned long long*)&Alds[8192 + s * 8];
                    dh[0] = h0; dh[1] = h1;
                    dl[0] = l0; dl[1] = l1;
                }
            }
            __syncthreads();
            #pragma unroll
            for (int kt = 0; kt < 16; ++kt) {
                int sA = ((col << 6) | ((kt * 4 + kg) ^ (col & 7))) * 8;
                short8 ahi = *(const short8*)&Alds[sA];
                short8 alo = *(const short8*)&Alds[8192 + sA];
                short8 bh = *(const short8*)(bbase + kt * 512);
                short8 bl = *(const short8*)(bbase + WIMG_HALF + kt * 512);
                acc = __builtin_amdgcn_mfma_f32_16x16x32_bf16(ahi, bh, acc, 0, 0, 0);
                acc = __builtin_amdgcn_mfma_f32_16x16x32_bf16(ahi, bl, acc, 0, 0, 0);
                acc = __builtin_amdgcn_mfma_f32_16x16x32_bf16(alo, bh, acc, 0, 0, 0);
            }
        }
        // all waves publish their gate tile
        xch[g][l][0] = acc[0] + g0v;
        xch[g][l][1] = acc[1] + g0v;
        xch[g][l][2] = acc[2] + g0v;
        xch[g][l][3] = acc[3] + g0v;
        __syncthreads();
        // spread epilogue: wave g handles j==g (math identical to R15)
        {
            float ip = xch[0][l][g];
            float fp = xch[1][l][g];
            float gp = xch[2][l][g];
            float op = xch[3][l][g];
            short* hw = hb + (size_t)(t & 1) * 131072;
            float i_ = 1.f / (1.f + expf(-ip));
            float f_ = 1.f / (1.f + expf(-fp));
            float gg = tanhf(gp);
            float o_ = 1.f / (1.f + expf(-op));
            float c_new = f_ * creg + i_ * gg;
            creg = c_new;
            float h = o_ * tanhf(c_new);
            Hs[(size_t)t * BD + epos] = h;
            short hi = f2bf(h);
            short lo = f2bf(h - bf2f(hi));
            hw[epos] = hi;
            hw[65536 + epos] = lo;
        }
        // arm the group flag (stores drained first)
        if (t + 1 < T_) {
            asm volatile("s_waitcnt vmcnt(0)" ::: "memory");
            __syncthreads();
            if (tid == 0) {
                if (!fast) __threadfence();
                __hip_atomic_fetch_add(bar + (size_t)(t * 8 + m) * 16, 1u,
                                       __ATOMIC_RELAXED, __HIP_MEMORY_SCOPE_AGENT);
            }
        }
    }
}

// ---------------------------------------------------------------- score -> w  (parallel over t)
__global__ void score_kernel(const float* __restrict__ enc, const float* __restrict__ Hs,
                             const double* __restrict__ rowsum, float* __restrict__ wout) {
    __shared__ float Hj[B_][68];
    __shared__ float Ei[B_][36];
    __shared__ float numer[64];
    const int tid = threadIdx.x;
    const int t  = blockIdx.x >> 3;
    const int j0 = (blockIdx.x & 7) * 64;
    for (int i = 0; i < 32; ++i) {
        int idx = i * 256 + tid;
        int bb = idx >> 6, jl = idx & 63;
        Hj[bb][jl] = Hs[(size_t)t * BD + bb * D_ + j0 + jl];
    }
    if (tid < 64) numer[tid] = 0.f;
    __syncthreads();
    const int ti = tid & 15;
    const int tj = tid >> 4;
    for (int itile = 0; itile < 16; ++itile) {
        int i0 = itile * 32;
        for (int i = 0; i < 16; ++i) {
            int idx = i * 256 + tid;
            int bb = idx >> 5, il = idx & 31;
            Ei[bb][il] = enc[(size_t)t * BD + bb * D_ + i0 + il];
        }
        __syncthreads();
        float a00=0,a01=0,a02=0,a03=0,a10=0,a11=0,a12=0,a13=0;
        #pragma unroll 4
        for (int bb = 0; bb < B_; ++bb) {
            float2 e2 = *(const float2*)&Ei[bb][ti * 2];
            float4 h4 = *(const float4*)&Hj[bb][tj * 4];
            a00 = fmaf(e2.x, h4.x, a00); a01 = fmaf(e2.x, h4.y, a01);
            a02 = fmaf(e2.x, h4.z, a02); a03 = fmaf(e2.x, h4.w, a03);
            a10 = fmaf(e2.y, h4.x, a10); a11 = fmaf(e2.y, h4.y, a11);
            a12 = fmaf(e2.y, h4.z, a12); a13 = fmaf(e2.y, h4.w, a13);
        }
        float v0 = expf(a00) + expf(a10);
        float v1 = expf(a01) + expf(a11);
        float v2 = expf(a02) + expf(a12);
        float v3 = expf(a03) + expf(a13);
        #pragma unroll
        for (int off = 1; off < 16; off <<= 1) {
            v0 += __shfl_xor(v0, off, 16);
            v1 += __shfl_xor(v1, off, 16);
            v2 += __shfl_xor(v2, off, 16);
            v3 += __shfl_xor(v3, off, 16);
        }
        if (ti == 0) {
            numer[tj * 4 + 0] += v0;
            numer[tj * 4 + 1] += v1;
            numer[tj * 4 + 2] += v2;
            numer[tj * 4 + 3] += v3;
        }
        __syncthreads();
    }
    if (tid < 64) {
        const double* rs = rowsum + t * B_;
        double dd = 0.0;
        for (int bb = 0; bb < B_; ++bb) dd += rs[bb] * (double)Hj[bb][tid];
        wout[t * D_ + j0 + tid] = (float)((double)numer[tid] / dd);
    }
}

// ---------------------------------------------------------------- u & hlog (parallel over t,b)
__global__ void ufuse_kernel(const float* __restrict__ enc, const float* __restrict__ Hs,
                             const float* __restrict__ wbuf, const float* __restrict__ WoT,
                             float* __restrict__ u, float* __restrict__ hlog) {
    int wave = threadIdx.x >> 6, lane = threadIdx.x & 63;
    int row = blockIdx.x * 4 + wave;        // row = t*B + b
    int t = row >> 7, b = row & 127;
    const float* Erow = enc + (size_t)row * D_;
    const float* Hrow = Hs  + (size_t)row * D_;
    const float* wrow = wbuf + t * D_;
    float ar[8], hr[8];
    #pragma unroll
    for (int k = 0; k < 8; ++k) {
        int j = k * 64 + lane;
        ar[k] = wrow[j] * Erow[j];
        hr[k] = Hrow[j];
    }
    for (int v = 0; v < V_; ++v) {
        const float* wo = WoT + v * TWO_D;
        float su = 0.f, sh = 0.f;
        #pragma unroll
        for (int k = 0; k < 8; ++k) {
            int j = k * 64 + lane;
            su = fmaf(ar[k], wo[D_ + j], su);
            sh = fmaf(hr[k], wo[j], sh);
        }
        for (int off = 32; off; off >>= 1) {
            su += __shfl_down(su, off, 64);
            sh += __shfl_down(sh, off, 64);
        }
        if (lane == 0) {
            u[(size_t)t * BV + b * V_ + v] = su;
            hlog[(size_t)row * V_ + v] = sh;
        }
    }
}

// ---------------------------------------------------------------- cumsum over t (in place)
__global__ void cumsum_kernel(float* __restrict__ u) {
    int bv = blockIdx.x * 256 + threadIdx.x;
    if (bv >= BV) return;
    float acc = 0.f;
    for (int t = 0; t < T_; ++t) {
        acc += u[(size_t)t * BV + bv];
        u[(size_t)t * BV + bv] = acc;
    }
}

// ---------------------------------------------------------------- log_softmax
__global__ void final_kernel(const float* __restrict__ hlog, const float* __restrict__ u,
                             const float* __restrict__ b_out, float* __restrict__ out) {
    int row = blockIdx.x * 256 + threadIdx.x;   // 65536 rows
    float logit[V_];
    float m = -INFINITY;
    #pragma unroll
    for (int v = 0; v < V_; ++v) {
        float x = hlog[(size_t)row * V_ + v] + u[(size_t)row * V_ + v] + b_out[v];
        logit[v] = x;
        m = fmaxf(m, x);
    }
    float s = 0.f;
    #pragma unroll
    for (int v = 0; v < V_; ++v) s += expf(logit[v] - m);
    float lse = m + logf(s);
    #pragma unroll
    for (int v = 0; v < V_; ++v) out[(size_t)row * V_ + v] = logit[v] - lse;
}

// ---------------------------------------------------------------- launch
extern "C" void kernel_launch(void* const* d_in, const int* in_sizes, int n_in,
                              void* d_out, int out_size, void* d_ws, size_t ws_size,
                              hipStream_t stream) {
    const float* enc   = (const float*)d_in[0];
    const float* b_emb = (const float*)d_in[2];
    const float* W_ih  = (const float*)d_in[3];
    const float* W_hh  = (const float*)d_in[4];
    const float* b_ih  = (const float*)d_in[5];
    const float* b_hh  = (const float*)d_in[6];
    const float* W_out = (const float*)d_in[7];
    const float* b_out = (const float*)d_in[8];
    float* out = (float*)d_out;

    char* p = (char*)d_ws;
    double* rowsum = (double*)p;              p += sizeof(double) * (size_t)T_ * B_;
    float* Hs      = (float*)p;               p += sizeof(float) * (size_t)T_ * BD;
    float* wbuf    = (float*)p;               p += sizeof(float) * (size_t)T_ * D_;
    float* u       = (float*)p;               p += sizeof(float) * (size_t)T_ * BV;
    float* hlog    = (float*)p;               p += sizeof(float) * (size_t)T_ * BV;
    float* g0      = (float*)p;               p += sizeof(float) * G4;
    float* WoT     = (float*)p;               p += sizeof(float) * V_ * TWO_D;
    short* Wimg    = (short*)p;               p += sizeof(short) * 2 * WIMG_HALF;
    short* hb      = (short*)p;               p += sizeof(short) * (2 * 131072 + 2 * BD);
    unsigned* bar  = (unsigned*)p;            p += sizeof(unsigned) * T_ * 8 * 16;
    unsigned* xinfo = (unsigned*)p;           p += sizeof(unsigned) * 256;

    hipMemsetAsync(bar, 0, sizeof(unsigned) * T_ * 8 * 16, stream);
    hipMemsetAsync(xinfo, 0, sizeof(unsigned) * 256, stream);
    prep_kernel<<<(G4 + V_ * TWO_D + 255) / 256, 256, 0, stream>>>(b_emb, W_ih, b_ih, b_hh, W_out, g0, WoT);
    prep2_kernel<<<(G4 * D_) / 256, 256, 0, stream>>>(W_hh, Wimg);
    rowsum_kernel<<<T_ * B_ / 4, 256, 0, stream>>>(enc, rowsum);
    {
        const short* Wimg_p = Wimg;
        const float* g0_p   = g0;
        float* Hs_p = Hs;
        short* hb_p = hb;
        unsigned* bar_p = bar;
        unsigned* xinfo_p = xinfo;
        void* args[] = { (void*)&Wimg_p, (void*)&g0_p, (void*)&Hs_p, (void*)&hb_p,
                         (void*)&bar_p, (void*)&xinfo_p };
        hipLaunchCooperativeKernel(lstm_persist, dim3(256), dim3(256), args, 0, stream);
    }
    score_kernel<<<T_ * 8, 256, 0, stream>>>(enc, Hs, rowsum, wbuf);
    ufuse_kernel<<<T_ * B_ / 4, 256, 0, stream>>>(enc, Hs, wbuf, WoT, u, hlog);
    cumsum_kernel<<<(BV + 255) / 256, 256, 0, stream>>>(u);
    final_kernel<<<T_ * B_ / 256, 256, 0, stream>>>(hlog, u, b_out, out);
}

// Round 17
// 5130.360 us; speedup vs baseline: 1.3503x; 1.3503x over previous
//
#include <hip/hip_runtime.h>
#include <hip/hip_cooperative_groups.h>
#include <math.h>

constexpr int T_ = 512, B_ = 128, D_ = 512, V_ = 33, E_ = 128;
constexpr int G4 = 4 * D_;          // 2048
constexpr int BD = B_ * D_;         // 65536
constexpr int BV = B_ * V_;         // 4224
constexpr int TWO_D = 2 * D_;       // 1024
constexpr int WIMG_HALF = 1048576;  // shorts per (hi|lo) plane of W image

typedef __attribute__((ext_vector_type(8))) short short8;
typedef __attribute__((ext_vector_type(4))) float floatx4;
typedef __attribute__((ext_vector_type(4))) int i32x4;

__device__ inline short f2bf(float f) {
    unsigned u = __float_as_uint(f);
    unsigned r = (u + 0x7fff + ((u >> 16) & 1)) >> 16;
    return (short)r;
}
__device__ inline float bf2f(short s) {
    return __uint_as_float(((unsigned)(unsigned short)s) << 16);
}

// ---------------------------------------------------------------- prep
__global__ void prep_kernel(const float* __restrict__ b_emb, const float* __restrict__ W_ih,
                            const float* __restrict__ b_ih, const float* __restrict__ b_hh,
                            const float* __restrict__ W_out,
                            float* __restrict__ g0, float* __restrict__ WoT) {
    int idx = blockIdx.x * 256 + threadIdx.x;
    if (idx < G4) {
        float acc = b_ih[idx] + b_hh[idx];
        for (int e = 0; e < E_; ++e) acc = fmaf(b_emb[e], W_ih[e * G4 + idx], acc);
        g0[idx] = acc;
    } else {
        int k = idx - G4;
        if (k < V_ * TWO_D) {
            int v = k / TWO_D, j = k % TWO_D;
            WoT[v * TWO_D + j] = W_out[j * V_ + v];
        }
    }
}

// ---------------------------------------------------------------- prep2: W fragment image
__global__ void prep2_kernel(const float* __restrict__ Whh, short* __restrict__ Wimg) {
    int idx = blockIdx.x * 256 + threadIdx.x;   // 2048*512 total
    int G = idx & 2047, k = idx >> 11;
    float v = Whh[(size_t)k * G4 + G];
    short hi = f2bf(v);
    short lo = f2bf(v - bf2f(hi));
    int g = G >> 9, cc = G & 511, n = cc >> 4, c = cc & 15;
    int kt = k >> 5, kg = (k >> 3) & 3, j = k & 7;
    int lane = kg * 16 + c;
    size_t dst = ((size_t)((n * 4 + g) * 16 + kt) * 64 + lane) * 8 + j;
    Wimg[dst] = hi;
    Wimg[dst + WIMG_HALF] = lo;
}

// ---------------------------------------------------------------- rowsum (f64)
__global__ void rowsum_kernel(const float* __restrict__ enc, double* __restrict__ rowsum) {
    int wave = threadIdx.x >> 6, lane = threadIdx.x & 63;
    int row = blockIdx.x * 4 + wave;
    const float* p = enc + (size_t)row * D_;
    double s = 0.0;
    #pragma unroll
    for (int k = 0; k < 8; ++k) s += (double)p[k * 64 + lane];
    for (int off = 32; off; off >>= 1) s += __shfl_down(s, off, 64);
    if (lane == 0) rowsum[row] = s;
}

// ---------------------------------------------------------------- lstm (persistent, XCD-local L2 exchange via sc0 loads)
// 256 blocks x 256 threads (cooperative, 1/CU). Block: m = blk&7, n = blk>>3.
// R16 confirmed on-silicon: each m-group sits on ONE XCD (8 groups / 8 XCDs).
// FAST path: producers' write-through stores land in the XCD L2; consumers
// read them with inline-asm global_load_dwordx4 sc0 (L1-miss, L2-hit) — no
// fences, no HBM. Load+waitcnt in ONE asm block (no hoisting hazard).
// Barrier: per-(t,m,n) relaxed flags; wave-0 lanes 0..31 spin 1 flag/lane.
// FALLBACK (mapping check fails): threadfence before arm / after spin.
// Per-step math, data layout, MFMA order, epilogue bit-identical to R15/R16.
__global__ void __launch_bounds__(256, 1) lstm_persist(const short* __restrict__ Wimg,
                                                       const float* __restrict__ g0,
                                                       float* __restrict__ Hs,
                                                       short* __restrict__ hb,
                                                       unsigned* __restrict__ bar,
                                                       unsigned* __restrict__ xinfo) {
    __shared__ short Alds[16384];            // 32 KB: A hi [0,8192) + lo [8192,16384)
    __shared__ float xch[4][64][4];
    __shared__ int fastflag;
    const int tid = threadIdx.x;
    const int l = tid & 63, g = tid >> 6;
    const int m = blockIdx.x & 7, n = blockIdx.x >> 3;
    const int col = l & 15, kg = l >> 4;
    const float g0v = g0[g * 512 + n * 16 + col];
    const short* __restrict__ bbase = Wimg + ((size_t)((n * 4 + g) * 16) * 64 + l) * 8;
    const int epos = (m * 16 + kg * 4 + g) * 512 + n * 16 + col;

    // ---- init: verify each m-group is XCD-local (adaptive gate, proven R16)
    if (tid == 0) {
        unsigned xcc = __builtin_amdgcn_s_getreg(6164) & 0xFu;  // HW_REG_XCC_ID(20), off 0, sz 4
        __hip_atomic_fetch_or(&xinfo[m * 16], 1u << xcc, __ATOMIC_RELAXED, __HIP_MEMORY_SCOPE_AGENT);
        __hip_atomic_fetch_add(&xinfo[128], 1u, __ATOMIC_RELAXED, __HIP_MEMORY_SCOPE_AGENT);
        while (__hip_atomic_load(&xinfo[128], __ATOMIC_RELAXED, __HIP_MEMORY_SCOPE_AGENT) < 256u)
            __builtin_amdgcn_s_sleep(1);
        unsigned orall = 0;
        int ok = 1;
        for (int i = 0; i < 8; ++i) {
            unsigned mk = __hip_atomic_load(&xinfo[i * 16], __ATOMIC_RELAXED, __HIP_MEMORY_SCOPE_AGENT);
            orall |= mk;
            if (__popc(mk) != 1) ok = 0;
        }
        if (orall != 0xFFu) ok = 0;
        fastflag = ok;
    }
    __syncthreads();
    const bool fast = (fastflag != 0);

    float creg = 0.f;

    for (int t = 0; t < T_; ++t) {
        floatx4 acc = {0.f, 0.f, 0.f, 0.f};
        if (t > 0) {
            // ---- wait for the 32 producers of row-group m (1 flag per lane)
            {
                const unsigned* fl = bar + ((size_t)(t - 1) * 8 + m) * 32;
                if (g == 0 && l < 32) {
                    while (!__hip_atomic_load(&fl[l], __ATOMIC_RELAXED, __HIP_MEMORY_SCOPE_AGENT))
                        __builtin_amdgcn_s_sleep(2);
                }
                __syncthreads();
                if (!fast) __threadfence();
            }
            // ---- stage A (32KB, swizzled): sc0 loads hit producer's L2
            {
                const short* ah = hb + (size_t)((t - 1) & 1) * 131072 + m * 8192;
                const short* al = ah + 65536;
                i32x4 H0, H1, H2, H3, L0, L1, L2, L3;
                asm volatile(
                    "global_load_dwordx4 %0, %8, off sc0\n\t"
                    "global_load_dwordx4 %1, %9, off sc0\n\t"
                    "global_load_dwordx4 %2, %10, off sc0\n\t"
                    "global_load_dwordx4 %3, %11, off sc0\n\t"
                    "global_load_dwordx4 %4, %12, off sc0\n\t"
                    "global_load_dwordx4 %5, %13, off sc0\n\t"
                    "global_load_dwordx4 %6, %14, off sc0\n\t"
                    "global_load_dwordx4 %7, %15, off sc0\n\t"
                    "s_waitcnt vmcnt(0)"
                    : "=&v"(H0), "=&v"(H1), "=&v"(H2), "=&v"(H3),
                      "=&v"(L0), "=&v"(L1), "=&v"(L2), "=&v"(L3)
                    : "v"(ah + (size_t)(0 * 256 + tid) * 8), "v"(ah + (size_t)(1 * 256 + tid) * 8),
                      "v"(ah + (size_t)(2 * 256 + tid) * 8), "v"(ah + (size_t)(3 * 256 + tid) * 8),
                      "v"(al + (size_t)(0 * 256 + tid) * 8), "v"(al + (size_t)(1 * 256 + tid) * 8),
                      "v"(al + (size_t)(2 * 256 + tid) * 8), "v"(al + (size_t)(3 * 256 + tid) * 8)
                    : "memory");
                int u0 = 0 * 256 + tid, u1 = 1 * 256 + tid, u2 = 2 * 256 + tid, u3 = 3 * 256 + tid;
                int s0 = (u0 & ~63) | ((u0 & 63) ^ ((u0 >> 6) & 7));
                int s1 = (u1 & ~63) | ((u1 & 63) ^ ((u1 >> 6) & 7));
                int s2 = (u2 & ~63) | ((u2 & 63) ^ ((u2 >> 6) & 7));
                int s3 = (u3 & ~63) | ((u3 & 63) ^ ((u3 >> 6) & 7));
                *(i32x4*)&Alds[s0 * 8] = H0;
                *(i32x4*)&Alds[s1 * 8] = H1;
                *(i32x4*)&Alds[s2 * 8] = H2;
                *(i32x4*)&Alds[s3 * 8] = H3;
                *(i32x4*)&Alds[8192 + s0 * 8] = L0;
                *(i32x4*)&Alds[8192 + s1 * 8] = L1;
                *(i32x4*)&Alds[8192 + s2 * 8] = L2;
                *(i32x4*)&Alds[8192 + s3 * 8] = L3;
            }
            __syncthreads();
            #pragma unroll
            for (int kt = 0; kt < 16; ++kt) {
                int sA = ((col << 6) | ((kt * 4 + kg) ^ (col & 7))) * 8;
                short8 ahi = *(const short8*)&Alds[sA];
                short8 alo = *(const short8*)&Alds[8192 + sA];
                short8 bh = *(const short8*)(bbase + kt * 512);
                short8 bl = *(const short8*)(bbase + WIMG_HALF + kt * 512);
                acc = __builtin_amdgcn_mfma_f32_16x16x32_bf16(ahi, bh, acc, 0, 0, 0);
                acc = __builtin_amdgcn_mfma_f32_16x16x32_bf16(ahi, bl, acc, 0, 0, 0);
                acc = __builtin_amdgcn_mfma_f32_16x16x32_bf16(alo, bh, acc, 0, 0, 0);
            }
        }
        // all waves publish their gate tile
        xch[g][l][0] = acc[0] + g0v;
        xch[g][l][1] = acc[1] + g0v;
        xch[g][l][2] = acc[2] + g0v;
        xch[g][l][3] = acc[3] + g0v;
        __syncthreads();
        // spread epilogue: wave g handles j==g (math identical to R15)
        {
            float ip = xch[0][l][g];
            float fp = xch[1][l][g];
            float gp = xch[2][l][g];
            float op = xch[3][l][g];
            short* hw = hb + (size_t)(t & 1) * 131072;
            float i_ = 1.f / (1.f + expf(-ip));
            float f_ = 1.f / (1.f + expf(-fp));
            float gg = tanhf(gp);
            float o_ = 1.f / (1.f + expf(-op));
            float c_new = f_ * creg + i_ * gg;
            creg = c_new;
            float h = o_ * tanhf(c_new);
            Hs[(size_t)t * BD + epos] = h;
            short hi = f2bf(h);
            short lo = f2bf(h - bf2f(hi));
            hw[epos] = hi;
            hw[65536 + epos] = lo;
        }
        // arm this block's flag (stores drained first)
        if (t + 1 < T_) {
            asm volatile("s_waitcnt vmcnt(0)" ::: "memory");
            __syncthreads();
            if (tid == 0) {
                if (!fast) __threadfence();
                __hip_atomic_store(&bar[((size_t)t * 8 + m) * 32 + n], 1u,
                                   __ATOMIC_RELAXED, __HIP_MEMORY_SCOPE_AGENT);
            }
        }
    }
}

// ---------------------------------------------------------------- score -> w  (parallel over t)
__global__ void score_kernel(const float* __restrict__ enc, const float* __restrict__ Hs,
                             const double* __restrict__ rowsum, float* __restrict__ wout) {
    __shared__ float Hj[B_][68];
    __shared__ float Ei[B_][36];
    __shared__ float numer[64];
    const int tid = threadIdx.x;
    const int t  = blockIdx.x >> 3;
    const int j0 = (blockIdx.x & 7) * 64;
    for (int i = 0; i < 32; ++i) {
        int idx = i * 256 + tid;
        int bb = idx >> 6, jl = idx & 63;
        Hj[bb][jl] = Hs[(size_t)t * BD + bb * D_ + j0 + jl];
    }
    if (tid < 64) numer[tid] = 0.f;
    __syncthreads();
    const int ti = tid & 15;
    const int tj = tid >> 4;
    for (int itile = 0; itile < 16; ++itile) {
        int i0 = itile * 32;
        for (int i = 0; i < 16; ++i) {
            int idx = i * 256 + tid;
            int bb = idx >> 5, il = idx & 31;
            Ei[bb][il] = enc[(size_t)t * BD + bb * D_ + i0 + il];
        }
        __syncthreads();
        float a00=0,a01=0,a02=0,a03=0,a10=0,a11=0,a12=0,a13=0;
        #pragma unroll 4
        for (int bb = 0; bb < B_; ++bb) {
            float2 e2 = *(const float2*)&Ei[bb][ti * 2];
            float4 h4 = *(const float4*)&Hj[bb][tj * 4];
            a00 = fmaf(e2.x, h4.x, a00); a01 = fmaf(e2.x, h4.y, a01);
            a02 = fmaf(e2.x, h4.z, a02); a03 = fmaf(e2.x, h4.w, a03);
            a10 = fmaf(e2.y, h4.x, a10); a11 = fmaf(e2.y, h4.y, a11);
            a12 = fmaf(e2.y, h4.z, a12); a13 = fmaf(e2.y, h4.w, a13);
        }
        float v0 = expf(a00) + expf(a10);
        float v1 = expf(a01) + expf(a11);
        float v2 = expf(a02) + expf(a12);
        float v3 = expf(a03) + expf(a13);
        #pragma unroll
        for (int off = 1; off < 16; off <<= 1) {
            v0 += __shfl_xor(v0, off, 16);
            v1 += __shfl_xor(v1, off, 16);
            v2 += __shfl_xor(v2, off, 16);
            v3 += __shfl_xor(v3, off, 16);
        }
        if (ti == 0) {
            numer[tj * 4 + 0] += v0;
            numer[tj * 4 + 1] += v1;
            numer[tj * 4 + 2] += v2;
            numer[tj * 4 + 3] += v3;
        }
        __syncthreads();
    }
    if (tid < 64) {
        const double* rs = rowsum + t * B_;
        double dd = 0.0;
        for (int bb = 0; bb < B_; ++bb) dd += rs[bb] * (double)Hj[bb][tid];
        wout[t * D_ + j0 + tid] = (float)((double)numer[tid] / dd);
    }
}

// ---------------------------------------------------------------- u & hlog (parallel over t,b)
__global__ void ufuse_kernel(const float* __restrict__ enc, const float* __restrict__ Hs,
                             const float* __restrict__ wbuf, const float* __restrict__ WoT,
                             float* __restrict__ u, float* __restrict__ hlog) {
    int wave = threadIdx.x >> 6, lane = threadIdx.x & 63;
    int row = blockIdx.x * 4 + wave;        // row = t*B + b
    int t = row >> 7, b = row & 127;
    const float* Erow = enc + (size_t)row * D_;
    const float* Hrow = Hs  + (size_t)row * D_;
    const float* wrow = wbuf + t * D_;
    float ar[8], hr[8];
    #pragma unroll
    for (int k = 0; k < 8; ++k) {
        int j = k * 64 + lane;
        ar[k] = wrow[j] * Erow[j];
        hr[k] = Hrow[j];
    }
    for (int v = 0; v < V_; ++v) {
        const float* wo = WoT + v * TWO_D;
        float su = 0.f, sh = 0.f;
        #pragma unroll
        for (int k = 0; k < 8; ++k) {
            int j = k * 64 + lane;
            su = fmaf(ar[k], wo[D_ + j], su);
            sh = fmaf(hr[k], wo[j], sh);
        }
        for (int off = 32; off; off >>= 1) {
            su += __shfl_down(su, off, 64);
            sh += __shfl_down(sh, off, 64);
        }
        if (lane == 0) {
            u[(size_t)t * BV + b * V_ + v] = su;
            hlog[(size_t)row * V_ + v] = sh;
        }
    }
}

// ---------------------------------------------------------------- cumsum over t (in place)
__global__ void cumsum_kernel(float* __restrict__ u) {
    int bv = blockIdx.x * 256 + threadIdx.x;
    if (bv >= BV) return;
    float acc = 0.f;
    for (int t = 0; t < T_; ++t) {
        acc += u[(size_t)t * BV + bv];
        u[(size_t)t * BV + bv] = acc;
    }
}

// ---------------------------------------------------------------- log_softmax
__global__ void final_kernel(const float* __restrict__ hlog, const float* __restrict__ u,
                             const float* __restrict__ b_out, float* __restrict__ out) {
    int row = blockIdx.x * 256 + threadIdx.x;   // 65536 rows
    float logit[V_];
    float m = -INFINITY;
    #pragma unroll
    for (int v = 0; v < V_; ++v) {
        float x = hlog[(size_t)row * V_ + v] + u[(size_t)row * V_ + v] + b_out[v];
        logit[v] = x;
        m = fmaxf(m, x);
    }
    float s = 0.f;
    #pragma unroll
    for (int v = 0; v < V_; ++v) s += expf(logit[v] - m);
    float lse = m + logf(s);
    #pragma unroll
    for (int v = 0; v < V_; ++v) out[(size_t)row * V_ + v] = logit[v] - lse;
}

// ---------------------------------------------------------------- launch
extern "C" void kernel_launch(void* const* d_in, const int* in_sizes, int n_in,
                              void* d_out, int out_size, void* d_ws, size_t ws_size,
                              hipStream_t stream) {
    const float* enc   = (const float*)d_in[0];
    const float* b_emb = (const float*)d_in[2];
    const float* W_ih  = (const float*)d_in[3];
    const float* W_hh  = (const float*)d_in[4];
    const float* b_ih  = (const float*)d_in[5];
    const float* b_hh  = (const float*)d_in[6];
    const float* W_out = (const float*)d_in[7];
    const float* b_out = (const float*)d_in[8];
    float* out = (float*)d_out;

    char* p = (char*)d_ws;
    double* rowsum = (double*)p;              p += sizeof(double) * (size_t)T_ * B_;
    float* Hs      = (float*)p;               p += sizeof(float) * (size_t)T_ * BD;
    float* wbuf    = (float*)p;               p += sizeof(float) * (size_t)T_ * D_;
    float* u       = (float*)p;               p += sizeof(float) * (size_t)T_ * BV;
    float* hlog    = (float*)p;               p += sizeof(float) * (size_t)T_ * BV;
    float* g0      = (float*)p;               p += sizeof(float) * G4;
    float* WoT     = (float*)p;               p += sizeof(float) * V_ * TWO_D;
    short* Wimg    = (short*)p;               p += sizeof(short) * 2 * WIMG_HALF;
    short* hb      = (short*)p;               p += sizeof(short) * (2 * 131072 + 2 * BD);
    unsigned* bar  = (unsigned*)p;            p += sizeof(unsigned) * T_ * 8 * 32;
    unsigned* xinfo = (unsigned*)p;           p += sizeof(unsigned) * 256;

    hipMemsetAsync(bar, 0, sizeof(unsigned) * T_ * 8 * 32, stream);
    hipMemsetAsync(xinfo, 0, sizeof(unsigned) * 256, stream);
    prep_kernel<<<(G4 + V_ * TWO_D + 255) / 256, 256, 0, stream>>>(b_emb, W_ih, b_ih, b_hh, W_out, g0, WoT);
    prep2_kernel<<<(G4 * D_) / 256, 256, 0, stream>>>(W_hh, Wimg);
    rowsum_kernel<<<T_ * B_ / 4, 256, 0, stream>>>(enc, rowsum);
    {
        const short* Wimg_p = Wimg;
        const float* g0_p   = g0;
        float* Hs_p = Hs;
        short* hb_p = hb;
        unsigned* bar_p = bar;
        unsigned* xinfo_p = xinfo;
        void* args[] = { (void*)&Wimg_p, (void*)&g0_p, (void*)&Hs_p, (void*)&hb_p,
                         (void*)&bar_p, (void*)&xinfo_p };
        hipLaunchCooperativeKernel(lstm_persist, dim3(256), dim3(256), args, 0, stream);
    }
    score_kernel<<<T_ * 8, 256, 0, stream>>>(enc, Hs, rowsum, wbuf);
    ufuse_kernel<<<T_ * B_ / 4, 256, 0, stream>>>(enc, Hs, wbuf, WoT, u, hlog);
    cumsum_kernel<<<(BV + 255) / 256, 256, 0, stream>>>(u);
    final_kernel<<<T_ * B_ / 256, 256, 0, stream>>>(hlog, u, b_out, out);
}

// Round 19
// 4356.137 us; speedup vs baseline: 1.5903x; 1.1777x over previous
//
#include <hip/hip_runtime.h>
#include <math.h>

constexpr int T_ = 512, B_ = 128, D_ = 512, V_ = 33, E_ = 128;
constexpr int G4 = 4 * D_;          // 2048
constexpr int BD = B_ * D_;         // 65536
constexpr int BV = B_ * V_;         // 4224
constexpr int TWO_D = 2 * D_;       // 1024
constexpr int WIMG_HALF = 1048576;  // shorts per (hi|lo) plane of W image

typedef __attribute__((ext_vector_type(8))) short short8;
typedef __attribute__((ext_vector_type(4))) float floatx4;

__device__ inline short f2bf(float f) {
    unsigned u = __float_as_uint(f);
    unsigned r = (u + 0x7fff + ((u >> 16) & 1)) >> 16;
    return (short)r;
}
__device__ inline float bf2f(short s) {
    return __uint_as_float(((unsigned)(unsigned short)s) << 16);
}

// ---------------------------------------------------------------- prep
__global__ void prep_kernel(const float* __restrict__ b_emb, const float* __restrict__ W_ih,
                            const float* __restrict__ b_ih, const float* __restrict__ b_hh,
                            const float* __restrict__ W_out,
                            float* __restrict__ g0, float* __restrict__ WoT) {
    int idx = blockIdx.x * 256 + threadIdx.x;
    if (idx < G4) {
        float acc = b_ih[idx] + b_hh[idx];
        for (int e = 0; e < E_; ++e) acc = fmaf(b_emb[e], W_ih[e * G4 + idx], acc);
        g0[idx] = acc;
    } else {
        int k = idx - G4;
        if (k < V_ * TWO_D) {
            int v = k / TWO_D, j = k % TWO_D;
            WoT[v * TWO_D + j] = W_out[j * V_ + v];
        }
    }
}

// ---------------------------------------------------------------- prep2: W fragment image
__global__ void prep2_kernel(const float* __restrict__ Whh, short* __restrict__ Wimg) {
    int idx = blockIdx.x * 256 + threadIdx.x;   // 2048*512 total
    int G = idx & 2047, k = idx >> 11;
    float v = Whh[(size_t)k * G4 + G];
    short hi = f2bf(v);
    short lo = f2bf(v - bf2f(hi));
    int g = G >> 9, cc = G & 511, n = cc >> 4, c = cc & 15;
    int kt = k >> 5, kg = (k >> 3) & 3, j = k & 7;
    int lane = kg * 16 + c;
    size_t dst = ((size_t)((n * 4 + g) * 16 + kt) * 64 + lane) * 8 + j;
    Wimg[dst] = hi;
    Wimg[dst + WIMG_HALF] = lo;
}

// ---------------------------------------------------------------- rowsum (f64)
__global__ void rowsum_kernel(const float* __restrict__ enc, double* __restrict__ rowsum) {
    int wave = threadIdx.x >> 6, lane = threadIdx.x & 63;
    int row = blockIdx.x * 4 + wave;
    const float* p = enc + (size_t)row * D_;
    double s = 0.0;
    #pragma unroll
    for (int k = 0; k < 8; ++k) s += (double)p[k * 64 + lane];
    for (int off = 32; off; off >>= 1) s += __shfl_down(s, off, 64);
    if (lane == 0) rowsum[row] = s;
}

// ---------------------------------------------------------------- lstm step (one timestep per launch)
// 256 blocks x 256 threads. Block: m = blk&7, n = blk>>3. R12 structure
// (A in swizzled LDS, B direct from L2, kernel-boundary sync) + R13's
// VERIFIED spread epilogue: all 4 waves write xch[4]; wave g computes
// gate-output j==g (1 output/thread). Per-output arithmetic bit-identical
// to R8-R13; c state in global f32 (same slots).
__global__ void __launch_bounds__(256, 1) lstm_step(const short* __restrict__ Wimg,
                                                    const float* __restrict__ g0,
                                                    float* __restrict__ Hs,
                                                    short* __restrict__ hb,
                                                    int t) {
    __shared__ short Alds[16384];            // 32 KB: A hi [0,8192) + lo [8192,16384)
    __shared__ float xch[4][64][4];
    const int tid = threadIdx.x;
    const int l = tid & 63, g = tid >> 6;
    const int m = blockIdx.x & 7, n = blockIdx.x >> 3;
    const int col = l & 15, kg = l >> 4;
    const float g0v = g0[g * 512 + n * 16 + col];
    const short* __restrict__ bbase = Wimg + ((size_t)((n * 4 + g) * 16) * 64 + l) * 8;
    // spread-epilogue ownership: this thread owns output (m*16+kg*4+g, n*16+col)
    const int epos = (m * 16 + kg * 4 + g) * 512 + n * 16 + col;

    floatx4 acc = {0.f, 0.f, 0.f, 0.f};
    if (t > 0) {
        // ---- stage A (32KB, swizzled 16B units), parallel across 256 threads
        {
            const short* ah = hb + (size_t)((t - 1) & 1) * 131072 + m * 8192;
            const short* al = ah + 65536;
            #pragma unroll
            for (int it = 0; it < 4; ++it) {
                int u = it * 256 + tid;                              // global 16B unit 0..1023
                int s = (u & ~63) | ((u & 63) ^ ((u >> 6) & 7));     // swizzled LDS unit
                *(short8*)&Alds[s * 8]        = *(const short8*)&ah[u * 8];
                *(short8*)&Alds[8192 + s * 8] = *(const short8*)&al[u * 8];
            }
        }
        __syncthreads();
        #pragma unroll
        for (int kt = 0; kt < 16; ++kt) {
            int sA = ((col << 6) | ((kt * 4 + kg) ^ (col & 7))) * 8;
            short8 ahi = *(const short8*)&Alds[sA];
            short8 alo = *(const short8*)&Alds[8192 + sA];
            short8 bh = *(const short8*)(bbase + kt * 512);
            short8 bl = *(const short8*)(bbase + WIMG_HALF + kt * 512);
            acc = __builtin_amdgcn_mfma_f32_16x16x32_bf16(ahi, bh, acc, 0, 0, 0);
            acc = __builtin_amdgcn_mfma_f32_16x16x32_bf16(ahi, bl, acc, 0, 0, 0);
            acc = __builtin_amdgcn_mfma_f32_16x16x32_bf16(alo, bh, acc, 0, 0, 0);
        }
    }
    // all waves publish their gate tile
    xch[g][l][0] = acc[0] + g0v;
    xch[g][l][1] = acc[1] + g0v;
    xch[g][l][2] = acc[2] + g0v;
    xch[g][l][3] = acc[3] + g0v;
    __syncthreads();
    // spread epilogue: wave g handles j==g for its 64 (kg,col) lanes
    {
        float ip = xch[0][l][g];
        float fp = xch[1][l][g];
        float gp = xch[2][l][g];
        float op = xch[3][l][g];
        float* cst = (float*)(hb + 2 * 131072);   // 128*512 f32 cell state
        short* hw = hb + (size_t)(t & 1) * 131072;
        float i_ = 1.f / (1.f + expf(-ip));
        float f_ = 1.f / (1.f + expf(-fp));
        float gg = tanhf(gp);
        float o_ = 1.f / (1.f + expf(-op));
        float cprev = (t > 0) ? cst[epos] : 0.f;
        float c_new = f_ * cprev + i_ * gg;
        cst[epos] = c_new;
        float h = o_ * tanhf(c_new);
        Hs[(size_t)t * BD + epos] = h;
        short hi = f2bf(h);
        short lo = f2bf(h - bf2f(hi));
        hw[epos] = hi;
        hw[65536 + epos] = lo;
    }
}

// ---------------------------------------------------------------- score -> w  (parallel over t)
__global__ void score_kernel(const float* __restrict__ enc, const float* __restrict__ Hs,
                             const double* __restrict__ rowsum, float* __restrict__ wout) {
    __shared__ float Hj[B_][68];
    __shared__ float Ei[B_][36];
    __shared__ float numer[64];
    const int tid = threadIdx.x;
    const int t  = blockIdx.x >> 3;
    const int j0 = (blockIdx.x & 7) * 64;
    for (int i = 0; i < 32; ++i) {
        int idx = i * 256 + tid;
        int bb = idx >> 6, jl = idx & 63;
        Hj[bb][jl] = Hs[(size_t)t * BD + bb * D_ + j0 + jl];
    }
    if (tid < 64) numer[tid] = 0.f;
    __syncthreads();
    const int ti = tid & 15;
    const int tj = tid >> 4;
    for (int itile = 0; itile < 16; ++itile) {
        int i0 = itile * 32;
        for (int i = 0; i < 16; ++i) {
            int idx = i * 256 + tid;
            int bb = idx >> 5, il = idx & 31;
            Ei[bb][il] = enc[(size_t)t * BD + bb * D_ + i0 + il];
        }
        __syncthreads();
        float a00=0,a01=0,a02=0,a03=0,a10=0,a11=0,a12=0,a13=0;
        #pragma unroll 4
        for (int bb = 0; bb < B_; ++bb) {
            float2 e2 = *(const float2*)&Ei[bb][ti * 2];
            float4 h4 = *(const float4*)&Hj[bb][tj * 4];
            a00 = fmaf(e2.x, h4.x, a00); a01 = fmaf(e2.x, h4.y, a01);
            a02 = fmaf(e2.x, h4.z, a02); a03 = fmaf(e2.x, h4.w, a03);
            a10 = fmaf(e2.y, h4.x, a10); a11 = fmaf(e2.y, h4.y, a11);
            a12 = fmaf(e2.y, h4.z, a12); a13 = fmaf(e2.y, h4.w, a13);
        }
        float v0 = expf(a00) + expf(a10);
        float v1 = expf(a01) + expf(a11);
        float v2 = expf(a02) + expf(a12);
        float v3 = expf(a03) + expf(a13);
        #pragma unroll
        for (int off = 1; off < 16; off <<= 1) {
            v0 += __shfl_xor(v0, off, 16);
            v1 += __shfl_xor(v1, off, 16);
            v2 += __shfl_xor(v2, off, 16);
            v3 += __shfl_xor(v3, off, 16);
        }
        if (ti == 0) {
            numer[tj * 4 + 0] += v0;
            numer[tj * 4 + 1] += v1;
            numer[tj * 4 + 2] += v2;
            numer[tj * 4 + 3] += v3;
        }
        __syncthreads();
    }
    if (tid < 64) {
        const double* rs = rowsum + t * B_;
        double dd = 0.0;
        for (int bb = 0; bb < B_; ++bb) dd += rs[bb] * (double)Hj[bb][tid];
        wout[t * D_ + j0 + tid] = (float)((double)numer[tid] / dd);
    }
}

// ---------------------------------------------------------------- u & hlog (parallel over t,b)
__global__ void ufuse_kernel(const float* __restrict__ enc, const float* __restrict__ Hs,
                             const float* __restrict__ wbuf, const float* __restrict__ WoT,
                             float* __restrict__ u, float* __restrict__ hlog) {
    int wave = threadIdx.x >> 6, lane = threadIdx.x & 63;
    int row = blockIdx.x * 4 + wave;        // row = t*B + b
    int t = row >> 7, b = row & 127;
    const float* Erow = enc + (size_t)row * D_;
    const float* Hrow = Hs  + (size_t)row * D_;
    const float* wrow = wbuf + t * D_;
    float ar[8], hr[8];
    #pragma unroll
    for (int k = 0; k < 8; ++k) {
        int j = k * 64 + lane;
        ar[k] = wrow[j] * Erow[j];
        hr[k] = Hrow[j];
    }
    for (int v = 0; v < V_; ++v) {
        const float* wo = WoT + v * TWO_D;
        float su = 0.f, sh = 0.f;
        #pragma unroll
        for (int k = 0; k < 8; ++k) {
            int j = k * 64 + lane;
            su = fmaf(ar[k], wo[D_ + j], su);
            sh = fmaf(hr[k], wo[j], sh);
        }
        for (int off = 32; off; off >>= 1) {
            su += __shfl_down(su, off, 64);
            sh += __shfl_down(sh, off, 64);
        }
        if (lane == 0) {
            u[(size_t)t * BV + b * V_ + v] = su;
            hlog[(size_t)row * V_ + v] = sh;
        }
    }
}

// ---------------------------------------------------------------- cumsum over t (in place)
__global__ void cumsum_kernel(float* __restrict__ u) {
    int bv = blockIdx.x * 256 + threadIdx.x;
    if (bv >= BV) return;
    float acc = 0.f;
    for (int t = 0; t < T_; ++t) {
        acc += u[(size_t)t * BV + bv];
        u[(size_t)t * BV + bv] = acc;
    }
}

// ---------------------------------------------------------------- log_softmax
__global__ void final_kernel(const float* __restrict__ hlog, const float* __restrict__ u,
                             const float* __restrict__ b_out, float* __restrict__ out) {
    int row = blockIdx.x * 256 + threadIdx.x;   // 65536 rows
    float logit[V_];
    float m = -INFINITY;
    #pragma unroll
    for (int v = 0; v < V_; ++v) {
        float x = hlog[(size_t)row * V_ + v] + u[(size_t)row * V_ + v] + b_out[v];
        logit[v] = x;
        m = fmaxf(m, x);
    }
    float s = 0.f;
    #pragma unroll
    for (int v = 0; v < V_; ++v) s += expf(logit[v] - m);
    float lse = m + logf(s);
    #pragma unroll
    for (int v = 0; v < V_; ++v) out[(size_t)row * V_ + v] = logit[v] - lse;
}

// ---------------------------------------------------------------- launch
extern "C" void kernel_launch(void* const* d_in, const int* in_sizes, int n_in,
                              void* d_out, int out_size, void* d_ws, size_t ws_size,
                              hipStream_t stream) {
    const float* enc   = (const float*)d_in[0];
    const float* b_emb = (const float*)d_in[2];
    const float* W_ih  = (const float*)d_in[3];
    const float* W_hh  = (const float*)d_in[4];
    const float* b_ih  = (const float*)d_in[5];
    const float* b_hh  = (const float*)d_in[6];
    const float* W_out = (const float*)d_in[7];
    const float* b_out = (const float*)d_in[8];
    float* out = (float*)d_out;

    char* p = (char*)d_ws;
    double* rowsum = (double*)p;              p += sizeof(double) * (size_t)T_ * B_;
    float* Hs      = (float*)p;               p += sizeof(float) * (size_t)T_ * BD;
    float* wbuf    = (float*)p;               p += sizeof(float) * (size_t)T_ * D_;
    float* u       = (float*)p;               p += sizeof(float) * (size_t)T_ * BV;
    float* hlog    = (float*)p;               p += sizeof(float) * (size_t)T_ * BV;
    float* g0      = (float*)p;               p += sizeof(float) * G4;
    float* WoT     = (float*)p;               p += sizeof(float) * V_ * TWO_D;
    short* Wimg    = (short*)p;               p += sizeof(short) * 2 * WIMG_HALF;
    short* hb      = (short*)p;               p += sizeof(short) * (2 * 131072 + 2 * BD); // 2 ping-pong planes + f32 c-state

    prep_kernel<<<(G4 + V_ * TWO_D + 255) / 256, 256, 0, stream>>>(b_emb, W_ih, b_ih, b_hh, W_out, g0, WoT);
    prep2_kernel<<<(G4 * D_) / 256, 256, 0, stream>>>(W_hh, Wimg);
    rowsum_kernel<<<T_ * B_ / 4, 256, 0, stream>>>(enc, rowsum);
    for (int t = 0; t < T_; ++t) {
        lstm_step<<<256, 256, 0, stream>>>(Wimg, g0, Hs, hb, t);
    }
    score_kernel<<<T_ * 8, 256, 0, stream>>>(enc, Hs, rowsum, wbuf);
    ufuse_kernel<<<T_ * B_ / 4, 256, 0, stream>>>(enc, Hs, wbuf, WoT, u, hlog);
    cumsum_kernel<<<(BV + 255) / 256, 256, 0, stream>>>(u);
    final_kernel<<<T_ * B_ / 256, 256, 0, stream>>>(hlog, u, b_out, out);
}